// Round 13
// baseline (183.563 us; speedup 1.0000x reference)
//
#include <hip/hip_runtime.h>

// ---------------------------------------------------------------------------
// Fused attention: x@Wqkv^T -> RoPE -> masked softmax attention -> @Wproj^T+b
// B=2, N=2048, C=1024, H=16, D=64.  All MFMA compute in bf16, fp32 accum.
//
// LESSON (R5): no scalar 2B global stores (16x HBM write amplification).
// LESSON (R10): unverified cross-lane primitives scrambled P<->V pairing;
// avoided via perm16 pre-permuted V/mask (R11, verified).
// LESSON (R12): XCD swizzle cut flash FETCH 69.7->12.4 MB; time barely moved.
// LESSON (R13): LDS staging is a COALESCING transform, not just a cache.
// LESSON (R14): TLP needs >=2 waves/SIMD; trading waves for DS traffic lost.
// LESSON (R15): flash is sum-of-pipes bound at ~50-52 us.  Parked.
// LESSON (R16): verify grid arithmetic before theorizing (768 != 192).
// R17 (WIN, 179.9): prep 32B/thread + fast trig (-5.7 us, matched pred).
//
// R18: RoPE-on-Q moved INTO flash (thread-local: partner d^32 = qraw[kd^2],
// jj=(kd&1)*16+hi*8+j, sgn=kd<2?-1:+1 — same formula as rope_scatter).
// flash reads raw Q from qkv (one-time gather, L2-hot); rope_scatter drops
// its Q path (-8MB read, -8MB write, -1/3 FMA).  Qm buffer now unused.
// ---------------------------------------------------------------------------

typedef __attribute__((ext_vector_type(8))) short          s16x8;
typedef __attribute__((ext_vector_type(8))) unsigned short u16x8;
typedef __attribute__((ext_vector_type(4))) unsigned short u16x4;
typedef __attribute__((ext_vector_type(4))) float          f32x4;
typedef __attribute__((ext_vector_type(16))) float         f32x16;
typedef __attribute__((ext_vector_type(4))) unsigned int   u32x4;

#define MFMA_BF16(a, b, c) __builtin_amdgcn_mfma_f32_16x16x32_bf16((a), (b), (c), 0, 0, 0)
#define MFMA32_BF16(a, b, c) __builtin_amdgcn_mfma_f32_32x32x16_bf16((a), (b), (c), 0, 0, 0)

// async global->LDS, 16B per lane (dest = wave-uniform base + lane*16)
#define GLD_TO_LDS(gp, lp) __builtin_amdgcn_global_load_lds(                  \
    (const __attribute__((address_space(1))) void*)(gp),                      \
    (__attribute__((address_space(3))) void*)(lp), 16, 0, 0)

__device__ __forceinline__ unsigned short f2bf(float f) {
    union { float f; unsigned int u; } v; v.f = f;
    unsigned int u = v.u;
    unsigned int r = u + 0x7FFFu + ((u >> 16) & 1u);   // round-to-nearest-even
    return (unsigned short)(r >> 16);
}
__device__ __forceinline__ float bf2f(unsigned short h) {
    union { unsigned int u; float f; } v; v.u = ((unsigned int)h) << 16;
    return v.f;
}
__device__ __forceinline__ f32x16 zero16() {
    f32x16 z;
#pragma unroll
    for (int i = 0; i < 16; i++) z[i] = 0.f;
    return z;
}
// pack two f32 -> one u32 of 2 bf16 (truncating): low half = a, high = b
__device__ __forceinline__ unsigned int pkbf(float a, float b) {
    return __builtin_amdgcn_perm(__builtin_bit_cast(unsigned int, b),
                                 __builtin_bit_cast(unsigned int, a), 0x07060302u);
}
// key permutation within a 16-block matching the 32x32 C/D row map
// (involution: swaps 4..7 <-> 8..11)
__device__ __forceinline__ int perm16(int p) {
    return (p & 3) + 8 * ((p >> 2) & 1) + 4 * (p >> 3);
}

// ---------------------------------------------------------------------------
// prep: fp32->bf16 converts (32B/thread) + mask -> perm16'd bf16 0/1 vector.
// Blocks: [0,2048) x, [2048,3584) w_qkv, [3584,4096) w_proj, [4096,4112) mask.
// ---------------------------------------------------------------------------
__global__ __launch_bounds__(256) void prep(const float* __restrict__ x,
                                            const float* __restrict__ wqkv,
                                            const float* __restrict__ wproj,
                                            const int* __restrict__ m,
                                            unsigned short* __restrict__ xb,
                                            unsigned short* __restrict__ wqkvb,
                                            unsigned short* __restrict__ wprojb,
                                            unsigned short* __restrict__ mb) {
    int blk = blockIdx.x, tid = threadIdx.x;
    if (blk < 4096) {
        const float* src; unsigned short* dst; int i;
        if (blk < 2048)      { src = x;     dst = xb;     i = blk * 256 + tid; }
        else if (blk < 3584) { src = wqkv;  dst = wqkvb;  i = (blk - 2048) * 256 + tid; }
        else                 { src = wproj; dst = wprojb; i = (blk - 3584) * 256 + tid; }
        f32x4 v0 = ((const f32x4*)src)[i * 2];
        f32x4 v1 = ((const f32x4*)src)[i * 2 + 1];
        u16x8 o;
        o[0] = f2bf(v0[0]); o[1] = f2bf(v0[1]); o[2] = f2bf(v0[2]); o[3] = f2bf(v0[3]);
        o[4] = f2bf(v1[0]); o[5] = f2bf(v1[1]); o[6] = f2bf(v1[2]); o[7] = f2bf(v1[3]);
        ((u16x8*)dst)[i] = o;
    } else {
        int i = (blk - 4096) * 256 + tid;
        int src = (i & ~15) | perm16(i & 15);          // N=2048 % 16 == 0: stays in batch
        mb[i] = (m[src] == 0) ? (unsigned short)0 : (unsigned short)0x3F80;  // bf16 1.0
    }
}

// ---------------------------------------------------------------------------
// bf16 GEMM, C[M,N] = A[M,K] * B[N,K]^T, bf16 out.  128x128 tile, BK=64.
// 1D grid, XCD-chunked swizzle (requires nwg % 8 == 0, else identity).
// ---------------------------------------------------------------------------
__global__ __launch_bounds__(256) void gemm_bt(const unsigned short* __restrict__ A,
                                               const unsigned short* __restrict__ B,
                                               unsigned short* __restrict__ C,
                                               int M, int N, int K) {
    __shared__ unsigned short Al[128][64];
    __shared__ unsigned short Bl[128][64];
    const int tid  = threadIdx.x;
    const int lane = tid & 63;
    const int qd   = lane >> 4;     // quad 0..3
    const int cc   = lane & 15;
    const int wave = tid >> 6;
    const int wr   = wave >> 1, wc = wave & 1;
    // XCD swizzle: chunk the grid so consecutive M-panels share an XCD L2
    const int nbx  = N >> 7;                     // N-tiles
    const int nwg  = gridDim.x;
    int d = blockIdx.x;
    int s = (nwg % 8 == 0) ? (d % 8) * (nwg / 8) + d / 8 : d;
    const int m0   = (s / nbx) * 128, n0 = (s % nbx) * 128;
    unsigned short* Alf = &Al[0][0];
    unsigned short* Blf = &Bl[0][0];

    f32x4 acc[4][4];
#pragma unroll
    for (int i = 0; i < 4; i++)
#pragma unroll
        for (int j = 0; j < 4; j++) acc[i][j] = (f32x4){0.f, 0.f, 0.f, 0.f};

    for (int k0 = 0; k0 < K; k0 += 64) {
#pragma unroll
        for (int t = 0; t < 4; t++) {
            int idx = t * 256 + tid;                 // 0..1023
            int row = idx >> 3, sg = (idx & 7) ^ (row & 7);
            GLD_TO_LDS(A + (size_t)(m0 + row) * K + k0 + sg * 8, Alf + idx * 8);
            GLD_TO_LDS(B + (size_t)(n0 + row) * K + k0 + sg * 8, Blf + idx * 8);
        }
        __syncthreads();
#pragma unroll
        for (int ks = 0; ks < 64; ks += 32) {
            const int s4 = ks >> 3;                  // 0 or 4
            s16x8 af[4], bf[4];
#pragma unroll
            for (int i = 0; i < 4; i++) {
                int r = wr * 64 + i * 16 + cc;
                af[i] = *(const s16x8*)&Al[r][((s4 + qd) ^ (r & 7)) * 8];
            }
#pragma unroll
            for (int j = 0; j < 4; j++) {
                int r = wc * 64 + j * 16 + cc;
                bf[j] = *(const s16x8*)&Bl[r][((s4 + qd) ^ (r & 7)) * 8];
            }
#pragma unroll
            for (int i = 0; i < 4; i++)
#pragma unroll
                for (int j = 0; j < 4; j++)
                    acc[i][j] = MFMA_BF16(af[i], bf[j], acc[i][j]);
        }
        __syncthreads();
    }
    // epilogue: C/D layout col=lane&15, row=quad*4+reg
#pragma unroll
    for (int i = 0; i < 4; i++)
#pragma unroll
        for (int j = 0; j < 4; j++)
#pragma unroll
            for (int r = 0; r < 4; r++) {
                int row = m0 + wr * 64 + i * 16 + qd * 4 + r;
                int col = n0 + wc * 64 + j * 16 + cc;
                C[(size_t)row * N + col] = f2bf(acc[i][j][r]);
            }
}

// ---------------------------------------------------------------------------
// RoPE + scatter (R18: K and V only; Q roped inside flash from qkv):
// qkv[4096,3072] bf16 -> K[B,H,N,D] (RoPE'd), V transposed -> Vt[B,H,D,N]
// with masked-key rows zeroed AND the key axis perm16-permuted within each
// 16-key block (flash PV B-frag order).  __cosf/__sinf fast trig.
// ---------------------------------------------------------------------------
__global__ __launch_bounds__(256) void rope_scatter(const unsigned short* __restrict__ qkv,
                                                    const int* __restrict__ msk,
                                                    unsigned short* __restrict__ Kg,
                                                    unsigned short* __restrict__ Vt) {
    const int N = 2048, H = 16, D = 64, C3 = 3072;
    __shared__ unsigned short vl[64][65];       // +1 pad for transpose reads
    const int nt = blockIdx.x, h = blockIdx.y, b = blockIdx.z;
    const int n0 = nt * 64;
    const int tid = threadIdx.x;
    const size_t bh = (size_t)b * H + h;
#pragma unroll
    for (int it = 0; it < 2; it++) {
        int idx = tid + it * 256;           // 0..511
        int row = idx >> 3, seg = idx & 7;
        int d0 = seg * 8;
        int n = n0 + row;
        size_t rb = ((size_t)b * N + n) * C3;
        int keep = msk[(size_t)b * N + n];
        u16x8 kv = *(const u16x8*)&qkv[rb + 1024 + h * 64 + d0];
        u16x8 kp = *(const u16x8*)&qkv[rb + 1024 + h * 64 + (d0 ^ 32)];
        u16x8 vv = *(const u16x8*)&qkv[rb + 2048 + h * 64 + d0];
        u16x8 ko;
        float sgn = (d0 < 32) ? -1.0f : 1.0f;   // rotate_half sign
#pragma unroll
        for (int j = 0; j < 8; j++) {
            int jj = (d0 & 31) + j;                              // freq index
            float th = (float)n * exp2f(-0.34375f * (float)jj);  // 2048^(-jj/32)
            float cth = __cosf(th), sth = __sinf(th);
            ko[j] = f2bf(bf2f(kv[j]) * cth + sgn * bf2f(kp[j]) * sth);
            vl[row][d0 + j] = keep ? vv[j] : (unsigned short)0;
        }
        *(u16x8*)&Kg[(bh * N + n) * D + d0] = ko;
    }
    __syncthreads();
    // transposed V write: Vt[b,h,d, n-permuted]: Vt[.., 16t+p] = V[16t+perm16(p)]
#pragma unroll
    for (int it = 0; it < 2; it++) {
        int idx = tid + it * 256;
        int drow = idx >> 3, nseg = idx & 7;
        u16x8 ov;
#pragma unroll
        for (int j = 0; j < 8; j++) {
            int cpos = nseg * 8 + j;
            int srcl = (cpos & ~15) | perm16(cpos & 15);
            ov[j] = vl[srcl][drow];
        }
        *(u16x8*)&Vt[(bh * D + drow) * N + n0 + nseg * 8] = ov;
    }
}

// ---------------------------------------------------------------------------
// Flash attention (R15 structure + R18 in-register Q-RoPE): 32x32x16 MFMA,
// key-split waves (qhalf = wave&1, khalf = wave>>1): each wave computes
// 64 q-rows x its 32-key half of every 64-key tile.  Raw Q read from qkv;
// RoPE applied thread-locally (partner d^32 = qraw[kd^2], jj=(kd&1)*16+
// hi*8+j, sgn=kd<2?-1:+1) with SCL folded in.  In-register P (R11 perm16),
// LDS-staged double-buffered K/V, XCD swizzle (512 = 8 x 64), cross-wave
// o/lacc reduction via LDS.
// ---------------------------------------------------------------------------
__global__ __launch_bounds__(256, 2) void flash_attn(const unsigned short* __restrict__ qkvp,
                                                     const unsigned short* __restrict__ Kg,
                                                     const unsigned short* __restrict__ Vt,
                                                     const unsigned short* __restrict__ mb,
                                                     unsigned short* __restrict__ Og) {
    const int N = 2048, H = 16, D = 64;
    const float SCL = 0.18033688f;              // 0.125 * log2(e)
    __shared__ unsigned short ldsbuf[4 * 64 * 64];   // 32KB: K0,K1,V0,V1 / reduction
    unsigned short (*Kl0)[64] = (unsigned short(*)[64])(ldsbuf);
    unsigned short (*Kl1)[64] = (unsigned short(*)[64])(ldsbuf + 4096);
    unsigned short (*Vl0)[64] = (unsigned short(*)[64])(ldsbuf + 8192);
    unsigned short (*Vl1)[64] = (unsigned short(*)[64])(ldsbuf + 12288);
    const int tid  = threadIdx.x;
    const int lane = tid & 63;
    const int wave = tid >> 6;                 // 0..3
    const int qhalf = wave & 1;                // q-rows [qhalf*64, +64)
    const int khalf = wave >> 1;               // keys [khalf*32, +32) of each tile
    const int c    = lane & 31;
    const int hi   = lane >> 5;
    // XCD swizzle: 512 blocks = 8 XCDs x 64; each XCD gets 4 (b,h) pairs
    int dd = blockIdx.x;
    int sw = (dd & 7) * 64 + (dd >> 3);
    const int qt = sw & 15, h = (sw >> 4) & 15, b = sw >> 8;
    const int q0 = qt * 128;
    const size_t bh = (size_t)b * H + h;

    // Q B-frags with in-register RoPE (B[n=q=lane&31][k=d=kd*16+hi*8+j]):
    s16x8 qf[2][4];
    {
        s16x8 qraw[2][4];
#pragma unroll
        for (int qs = 0; qs < 2; qs++) {
            const unsigned short* Qb =
                qkvp + ((size_t)b * N + q0 + qhalf * 64 + qs * 32 + c) * 3072 + h * 64;
#pragma unroll
            for (int kd = 0; kd < 4; kd++)
                qraw[qs][kd] = *(const s16x8*)(Qb + kd * 16 + hi * 8);
        }
#pragma unroll
        for (int qs = 0; qs < 2; qs++) {
            float nn = (float)(q0 + qhalf * 64 + qs * 32 + c);
#pragma unroll
            for (int kd = 0; kd < 4; kd++) {
                float sgn = (kd < 2) ? -1.0f : 1.0f;     // rotate_half sign (d<32)
#pragma unroll
                for (int j = 0; j < 8; j++) {
                    int jj = (kd & 1) * 16 + hi * 8 + j;               // d & 31
                    float th = nn * exp2f(-0.34375f * (float)jj);
                    float cth = __cosf(th), sth = __sinf(th);
                    float v = bf2f((unsigned short)qraw[qs][kd][j]);
                    float p = bf2f((unsigned short)qraw[qs][kd ^ 2][j]); // d ^ 32
                    qf[qs][kd][j] = (short)f2bf((v * cth + sgn * p * sth) * SCL);
                }
            }
        }
    }

    f32x16 o[2][2], lacc[2];
#pragma unroll
    for (int qs = 0; qs < 2; qs++) {
        o[qs][0] = zero16(); o[qs][1] = zero16(); lacc[qs] = zero16();
    }

    const unsigned short* Kbase = Kg + bh * N * D;
    const unsigned short* Vbase = Vt + bh * D * N;
    const unsigned short* mbase = mb + (size_t)b * N;   // perm16'd bf16 0/1 mask
    const int row_s = tid >> 3, sg_s = (tid & 7) ^ ((tid >> 3) & 7);
    const int row_s2 = (tid + 256) >> 3, sg_s2 = (tid & 7) ^ (((tid + 256) >> 3) & 7);

    auto issue = [&](int k0, unsigned short* Kb, unsigned short* Vb) {
        GLD_TO_LDS(Kbase + (size_t)(k0 + row_s) * D + sg_s * 8,   Kb + tid * 8);
        GLD_TO_LDS(Vbase + (size_t)row_s * N + k0 + sg_s * 8,     Vb + tid * 8);
        GLD_TO_LDS(Kbase + (size_t)(k0 + row_s2) * D + sg_s2 * 8, Kb + (tid + 256) * 8);
        GLD_TO_LDS(Vbase + (size_t)row_s2 * N + k0 + sg_s2 * 8,   Vb + (tid + 256) * 8);
    };

    auto compute = [&](int k0, const unsigned short (*Kb)[64], const unsigned short (*Vb)[64]) {
        // exp2 + DIRECT in-register pack (R11 layout: keys perm16'd in V/mask)
        auto packkg = [&](const f32x16& sstv, s16x8* pa) {
            float p[16];
#pragma unroll
            for (int r = 0; r < 16; r++) p[r] = __builtin_amdgcn_exp2f(sstv[r]);
#pragma unroll
            for (int half = 0; half < 2; half++) {
                int bs = half * 8;
                u32x4 w = { pkbf(p[bs + 0], p[bs + 1]), pkbf(p[bs + 2], p[bs + 3]),
                            pkbf(p[bs + 4], p[bs + 5]), pkbf(p[bs + 6], p[bs + 7]) };
                pa[half] = __builtin_bit_cast(s16x8, w);
            }
        };

        // ---- QK^T on this wave's 32-key half, both q-sub-blocks ----------
        int kr = khalf * 32 + c;
        s16x8 kf[4];
#pragma unroll
        for (int kd = 0; kd < 4; kd++)
            kf[kd] = *(const s16x8*)&Kb[kr][((kd * 2 + hi) ^ (kr & 7)) * 8];
        f32x16 sst0 = zero16(), sst1 = zero16();
        __builtin_amdgcn_s_setprio(1);
#pragma unroll
        for (int kd = 0; kd < 4; kd++) {
            sst0 = MFMA32_BF16(kf[kd], qf[0][kd], sst0);
            sst1 = MFMA32_BF16(kf[kd], qf[1][kd], sst1);
        }
        __builtin_amdgcn_s_setprio(0);
        s16x8 pa[2][2];                    // [qs][ksl]
        packkg(sst0, pa[0]);
        packkg(sst1, pa[1]);

        // ---- O += P V ; l += P @ mask on the wave's two 16-key slices ----
#pragma unroll
        for (int ksl = 0; ksl < 2; ksl++) {
            int ks = khalf * 2 + ksl;      // global 16-key slice
            s16x8 mfr = *(const s16x8*)&mbase[k0 + ks * 16 + hi * 8];
            int vr0 = c, vr1 = 32 + c;
            s16x8 vf0 = *(const s16x8*)&Vb[vr0][((ks * 2 + hi) ^ (vr0 & 7)) * 8];
            s16x8 vf1 = *(const s16x8*)&Vb[vr1][((ks * 2 + hi) ^ (vr1 & 7)) * 8];
            __builtin_amdgcn_s_setprio(1);
#pragma unroll
            for (int qs = 0; qs < 2; qs++) {
                lacc[qs]  = MFMA32_BF16(pa[qs][ksl], mfr, lacc[qs]);
                o[qs][0]  = MFMA32_BF16(pa[qs][ksl], vf0, o[qs][0]);
                o[qs][1]  = MFMA32_BF16(pa[qs][ksl], vf1, o[qs][1]);
            }
            __builtin_amdgcn_s_setprio(0);
        }
    };

    issue(0, &Kl0[0][0], &Vl0[0][0]);
    __syncthreads();
    for (int it = 0; it < 32; it += 2) {
        int k0 = it * 64;
        if (it + 1 < 32) issue(k0 + 64, &Kl1[0][0], &Vl1[0][0]);
        compute(k0, Kl0, Vl0);
        __syncthreads();
        if (it + 2 < 32) issue(k0 + 128, &Kl0[0][0], &Vl0[0][0]);
        compute(k0 + 64, Kl1, Vl1);
        __syncthreads();
    }

    // ---- cross-wave reduction: khalf=1 partials -> khalf=0 ---------------
    // stride 49 floats/lane -> bank (lane*17 + r) % 32, conflict-free.
    float* red = (float*)ldsbuf;
#pragma unroll
    for (int qs = 0; qs < 2; qs++) {
        __syncthreads();
        if (khalf == 1) {
            float* dst = red + qhalf * 3136 + lane * 49;
#pragma unroll
            for (int r = 0; r < 16; r++) {
                dst[r] = o[qs][0][r]; dst[16 + r] = o[qs][1][r]; dst[32 + r] = lacc[qs][r];
            }
        }
        __syncthreads();
        if (khalf == 0) {
            const float* src = red + qhalf * 3136 + lane * 49;
#pragma unroll
            for (int r = 0; r < 16; r++) {
                o[qs][0][r] += src[r]; o[qs][1][r] += src[16 + r]; lacc[qs][r] += src[32 + r];
            }
        }
    }

    // epilogue (khalf==0 waves): row q = q0+qhalf*64+qs*32+(r&3)+8(r>>2)+4hi
    if (khalf == 0) {
#pragma unroll
        for (int qs = 0; qs < 2; qs++) {
            float linv[16];
#pragma unroll
            for (int r = 0; r < 16; r++) linv[r] = 1.0f / lacc[qs][r];
#pragma unroll
            for (int db = 0; db < 2; db++)
#pragma unroll
                for (int r = 0; r < 16; r++) {
                    int n = q0 + qhalf * 64 + qs * 32 + (r & 3) + 8 * (r >> 2) + 4 * hi;
                    Og[((size_t)b * N + n) * 1024 + h * 64 + db * 32 + c] =
                        f2bf(o[qs][db][r] * linv[r]);
                }
        }
    }
}

// ---------------------------------------------------------------------------
// Projection GEMM: out[4096,1024] = attno[4096,1024] @ w_proj^T + bias, fp32.
// 1D grid (512 = 8 x 64), XCD-chunked swizzle.
// ---------------------------------------------------------------------------
__global__ __launch_bounds__(256) void gemm_proj(const unsigned short* __restrict__ A,
                                                 const unsigned short* __restrict__ B,
                                                 float* __restrict__ C,
                                                 const float* __restrict__ bias) {
    const int NN = 1024, K = 1024;
    __shared__ unsigned short Al[128][64];
    __shared__ unsigned short Bl[64][64];
    const int tid  = threadIdx.x;
    const int lane = tid & 63;
    const int qd   = lane >> 4;
    const int cc   = lane & 15;
    const int wave = tid >> 6;
    const int wr   = wave >> 1, wc = wave & 1;
    int dd = blockIdx.x;                        // 512 = 8 x 64
    int sw = (dd & 7) * 64 + (dd >> 3);
    const int m0   = (sw >> 4) * 128, n0 = (sw & 15) * 64;
    unsigned short* Alf = &Al[0][0];
    unsigned short* Blf = &Bl[0][0];

    f32x4 acc[4][2];
#pragma unroll
    for (int i = 0; i < 4; i++)
#pragma unroll
        for (int j = 0; j < 2; j++) acc[i][j] = (f32x4){0.f, 0.f, 0.f, 0.f};

    for (int k0 = 0; k0 < K; k0 += 64) {
#pragma unroll
        for (int t = 0; t < 4; t++) {
            int idx = t * 256 + tid;
            int row = idx >> 3, sg = (idx & 7) ^ (row & 7);
            GLD_TO_LDS(A + (size_t)(m0 + row) * K + k0 + sg * 8, Alf + idx * 8);
        }
#pragma unroll
        for (int t = 0; t < 2; t++) {
            int idx = t * 256 + tid;
            int row = idx >> 3, sg = (idx & 7) ^ (row & 7);
            GLD_TO_LDS(B + (size_t)(n0 + row) * K + k0 + sg * 8, Blf + idx * 8);
        }
        __syncthreads();
#pragma unroll
        for (int ks = 0; ks < 64; ks += 32) {
            const int s4 = ks >> 3;
            s16x8 af[4], bf[2];
#pragma unroll
            for (int i = 0; i < 4; i++) {
                int r = wr * 64 + i * 16 + cc;
                af[i] = *(const s16x8*)&Al[r][((s4 + qd) ^ (r & 7)) * 8];
            }
#pragma unroll
            for (int j = 0; j < 2; j++) {
                int r = wc * 32 + j * 16 + cc;
                bf[j] = *(const s16x8*)&Bl[r][((s4 + qd) ^ (r & 7)) * 8];
            }
#pragma unroll
            for (int i = 0; i < 4; i++)
#pragma unroll
                for (int j = 0; j < 2; j++)
                    acc[i][j] = MFMA_BF16(af[i], bf[j], acc[i][j]);
        }
        __syncthreads();
    }
#pragma unroll
    for (int i = 0; i < 4; i++)
#pragma unroll
        for (int j = 0; j < 2; j++)
#pragma unroll
            for (int r = 0; r < 4; r++) {
                int row = m0 + wr * 64 + i * 16 + qd * 4 + r;
                int col = n0 + wc * 32 + j * 16 + cc;
                C[(size_t)row * NN + col] = acc[i][j][r] + bias[col];
            }
}

// ---------------------------------------------------------------------------
extern "C" void kernel_launch(void* const* d_in, const int* in_sizes, int n_in,
                              void* d_out, int out_size, void* d_ws, size_t ws_size,
                              hipStream_t stream) {
    const float* x      = (const float*)d_in[0];
    const float* w_qkv  = (const float*)d_in[1];
    const float* w_proj = (const float*)d_in[2];
    const float* b_proj = (const float*)d_in[3];
    const int*   mask   = (const int*)d_in[4];
    float* out = (float*)d_out;

    // workspace layout (bf16 elements), ~72 MB
    unsigned short* ws     = (unsigned short*)d_ws;
    unsigned short* xb     = ws;                                  // 4096*1024
    unsigned short* wqkvb  = xb     + (size_t)4096 * 1024;        // 3072*1024
    unsigned short* wprojb = wqkvb  + (size_t)3072 * 1024;        // 1024*1024
    unsigned short* qkv    = wprojb + (size_t)1024 * 1024;        // 4096*3072
    unsigned short* Qm     = qkv    + (size_t)4096 * 3072;        // unused (R18)
    unsigned short* Km     = Qm     + (size_t)32 * 2048 * 64;
    unsigned short* Vtm    = Km     + (size_t)32 * 2048 * 64;
    unsigned short* attno  = Vtm    + (size_t)32 * 2048 * 64;     // 4096*1024
    unsigned short* maskbf = attno  + (size_t)4096 * 1024;        // 2*2048 bf16

    // converts (32B/thread) + perm16'd bf16 mask vector, one launch
    prep<<<4112, 256, 0, stream>>>(x, w_qkv, w_proj, mask, xb, wqkvb, wprojb, maskbf);
    // qkv = x @ w_qkv^T   [4096, 3072]   (768 blocks = 8 x 96, XCD-swizzled)
    gemm_bt<<<768, 256, 0, stream>>>(xb, wqkvb, qkv, 4096, 3072, 1024);
    // RoPE + scatter: K [B,H,N,D] RoPE'd; Vt [B,H,D,N] perm16'd + masked rows zeroed
    rope_scatter<<<dim3(32, 16, 2), 256, 0, stream>>>(qkv, mask, Km, Vtm);
    // attention: 128-row Q tiles, key-split waves, 32x32 MFMA, in-reg P,
    // in-reg Q-RoPE from qkv, LDS-staged K/V  (512 blocks = 8 x 64, XCD-swizzled)
    flash_attn<<<512, 256, 0, stream>>>(qkv, Km, Vtm, maskbf, attno);
    // out = attn_out @ w_proj^T + b_proj   (512 blocks = 8 x 64, XCD-swizzled)
    gemm_proj<<<512, 256, 0, stream>>>(attno, wprojb, out, b_proj);
}

// Round 14
// 179.070 us; speedup vs baseline: 1.0251x; 1.0251x over previous
//
#include <hip/hip_runtime.h>

// ---------------------------------------------------------------------------
// Fused attention: x@Wqkv^T -> RoPE -> masked softmax attention -> @Wproj^T+b
// B=2, N=2048, C=1024, H=16, D=64.  All MFMA compute in bf16, fp32 accum.
//
// LESSON (R5): no scalar 2B global stores (16x HBM write amplification) —
// 32B-coalesced per-16-lane chunks (the GEMM epilogue pattern) are fine.
// LESSON (R10): unverified cross-lane primitives scrambled P<->V pairing;
// avoided via perm16 pre-permuted V/mask (R11, verified).
// LESSON (R13): LDS staging is a COALESCING transform, not just a cache.
// LESSON (R14/R15): flash is sum-of-pipes bound at ~51 us.  Parked.
// LESSON (R16): verify grid arithmetic before theorizing.
// LESSON (R18): e2e noise is +-2-4 us; per-kernel dur is the reliable signal.
// R17 (WIN, 179.9): prep 32B/thread + fast trig.
// R18 (neutral): Q-RoPE moved into flash (thread-local j^2 partner trick).
//
// R19: K-RoPE moved into gemm_bt's epilogue for K-region tiles (n0 in
// [1024,2048)): d=j*16+cc, partner d^32 = acc[i][j^2][r] (same lane),
// roped from fp32 accumulators, written straight to Km[b,h,n,d] with the
// same 32B-coalesced stores.  qkv K-region never written.  rope_scatter ->
// v_scatter (V-only: mask-zero + perm16 transpose, zero trig).
// ---------------------------------------------------------------------------

typedef __attribute__((ext_vector_type(8))) short          s16x8;
typedef __attribute__((ext_vector_type(8))) unsigned short u16x8;
typedef __attribute__((ext_vector_type(4))) unsigned short u16x4;
typedef __attribute__((ext_vector_type(4))) float          f32x4;
typedef __attribute__((ext_vector_type(16))) float         f32x16;
typedef __attribute__((ext_vector_type(4))) unsigned int   u32x4;

#define MFMA_BF16(a, b, c) __builtin_amdgcn_mfma_f32_16x16x32_bf16((a), (b), (c), 0, 0, 0)
#define MFMA32_BF16(a, b, c) __builtin_amdgcn_mfma_f32_32x32x16_bf16((a), (b), (c), 0, 0, 0)

// async global->LDS, 16B per lane (dest = wave-uniform base + lane*16)
#define GLD_TO_LDS(gp, lp) __builtin_amdgcn_global_load_lds(                  \
    (const __attribute__((address_space(1))) void*)(gp),                      \
    (__attribute__((address_space(3))) void*)(lp), 16, 0, 0)

__device__ __forceinline__ unsigned short f2bf(float f) {
    union { float f; unsigned int u; } v; v.f = f;
    unsigned int u = v.u;
    unsigned int r = u + 0x7FFFu + ((u >> 16) & 1u);   // round-to-nearest-even
    return (unsigned short)(r >> 16);
}
__device__ __forceinline__ float bf2f(unsigned short h) {
    union { unsigned int u; float f; } v; v.u = ((unsigned int)h) << 16;
    return v.f;
}
__device__ __forceinline__ f32x16 zero16() {
    f32x16 z;
#pragma unroll
    for (int i = 0; i < 16; i++) z[i] = 0.f;
    return z;
}
// pack two f32 -> one u32 of 2 bf16 (truncating): low half = a, high = b
__device__ __forceinline__ unsigned int pkbf(float a, float b) {
    return __builtin_amdgcn_perm(__builtin_bit_cast(unsigned int, b),
                                 __builtin_bit_cast(unsigned int, a), 0x07060302u);
}
// key permutation within a 16-block matching the 32x32 C/D row map
// (involution: swaps 4..7 <-> 8..11)
__device__ __forceinline__ int perm16(int p) {
    return (p & 3) + 8 * ((p >> 2) & 1) + 4 * (p >> 3);
}

// ---------------------------------------------------------------------------
// prep: fp32->bf16 converts (32B/thread) + mask -> perm16'd bf16 0/1 vector.
// Blocks: [0,2048) x, [2048,3584) w_qkv, [3584,4096) w_proj, [4096,4112) mask.
// ---------------------------------------------------------------------------
__global__ __launch_bounds__(256) void prep(const float* __restrict__ x,
                                            const float* __restrict__ wqkv,
                                            const float* __restrict__ wproj,
                                            const int* __restrict__ m,
                                            unsigned short* __restrict__ xb,
                                            unsigned short* __restrict__ wqkvb,
                                            unsigned short* __restrict__ wprojb,
                                            unsigned short* __restrict__ mb) {
    int blk = blockIdx.x, tid = threadIdx.x;
    if (blk < 4096) {
        const float* src; unsigned short* dst; int i;
        if (blk < 2048)      { src = x;     dst = xb;     i = blk * 256 + tid; }
        else if (blk < 3584) { src = wqkv;  dst = wqkvb;  i = (blk - 2048) * 256 + tid; }
        else                 { src = wproj; dst = wprojb; i = (blk - 3584) * 256 + tid; }
        f32x4 v0 = ((const f32x4*)src)[i * 2];
        f32x4 v1 = ((const f32x4*)src)[i * 2 + 1];
        u16x8 o;
        o[0] = f2bf(v0[0]); o[1] = f2bf(v0[1]); o[2] = f2bf(v0[2]); o[3] = f2bf(v0[3]);
        o[4] = f2bf(v1[0]); o[5] = f2bf(v1[1]); o[6] = f2bf(v1[2]); o[7] = f2bf(v1[3]);
        ((u16x8*)dst)[i] = o;
    } else {
        int i = (blk - 4096) * 256 + tid;
        int src = (i & ~15) | perm16(i & 15);          // N=2048 % 16 == 0: stays in batch
        mb[i] = (m[src] == 0) ? (unsigned short)0 : (unsigned short)0x3F80;  // bf16 1.0
    }
}

// ---------------------------------------------------------------------------
// bf16 GEMM, C[M,N] = A[M,K] * B[N,K]^T.  128x128 tile, BK=64, 768 blocks.
// R19 epilogue: K-region tiles (n0 in [1024,2048)) apply RoPE in-register
// (partner d^32 = acc[i][j^2][r], same lane) and write Km[b,h,n,d] directly;
// other tiles write bf16 C (qkv) as before.  XCD-chunked swizzle.
// ---------------------------------------------------------------------------
__global__ __launch_bounds__(256) void gemm_bt(const unsigned short* __restrict__ A,
                                               const unsigned short* __restrict__ B,
                                               unsigned short* __restrict__ C,
                                               unsigned short* __restrict__ Km,
                                               int M, int N, int K) {
    __shared__ unsigned short Al[128][64];
    __shared__ unsigned short Bl[128][64];
    const int tid  = threadIdx.x;
    const int lane = tid & 63;
    const int qd   = lane >> 4;     // quad 0..3
    const int cc   = lane & 15;
    const int wave = tid >> 6;
    const int wr   = wave >> 1, wc = wave & 1;
    // XCD swizzle: chunk the grid so consecutive M-panels share an XCD L2
    const int nbx  = N >> 7;                     // N-tiles
    const int nwg  = gridDim.x;
    int d = blockIdx.x;
    int s = (nwg % 8 == 0) ? (d % 8) * (nwg / 8) + d / 8 : d;
    const int m0   = (s / nbx) * 128, n0 = (s % nbx) * 128;
    unsigned short* Alf = &Al[0][0];
    unsigned short* Blf = &Bl[0][0];

    f32x4 acc[4][4];
#pragma unroll
    for (int i = 0; i < 4; i++)
#pragma unroll
        for (int j = 0; j < 4; j++) acc[i][j] = (f32x4){0.f, 0.f, 0.f, 0.f};

    for (int k0 = 0; k0 < K; k0 += 64) {
#pragma unroll
        for (int t = 0; t < 4; t++) {
            int idx = t * 256 + tid;                 // 0..1023
            int row = idx >> 3, sg = (idx & 7) ^ (row & 7);
            GLD_TO_LDS(A + (size_t)(m0 + row) * K + k0 + sg * 8, Alf + idx * 8);
            GLD_TO_LDS(B + (size_t)(n0 + row) * K + k0 + sg * 8, Blf + idx * 8);
        }
        __syncthreads();
#pragma unroll
        for (int ks = 0; ks < 64; ks += 32) {
            const int s4 = ks >> 3;                  // 0 or 4
            s16x8 af[4], bf[4];
#pragma unroll
            for (int i = 0; i < 4; i++) {
                int r = wr * 64 + i * 16 + cc;
                af[i] = *(const s16x8*)&Al[r][((s4 + qd) ^ (r & 7)) * 8];
            }
#pragma unroll
            for (int j = 0; j < 4; j++) {
                int r = wc * 64 + j * 16 + cc;
                bf[j] = *(const s16x8*)&Bl[r][((s4 + qd) ^ (r & 7)) * 8];
            }
#pragma unroll
            for (int i = 0; i < 4; i++)
#pragma unroll
                for (int j = 0; j < 4; j++)
                    acc[i][j] = MFMA_BF16(af[i], bf[j], acc[i][j]);
        }
        __syncthreads();
    }
    // epilogue: C/D layout col=lane&15, row=quad*4+reg
    if (n0 >= 1024 && n0 < 2048) {
        // K region: in-register RoPE (from fp32 acc), write Km[b,h,n,d].
#pragma unroll
        for (int i = 0; i < 4; i++)
#pragma unroll
            for (int r = 0; r < 4; r++) {
                int row = m0 + wr * 64 + i * 16 + qd * 4 + r;   // token index
                int bb = row >> 11, n = row & 2047;
                float cth[2], sth[2];
#pragma unroll
                for (int p2 = 0; p2 < 2; p2++) {
                    float th = (float)n * exp2f(-0.34375f * (float)(p2 * 16 + cc));
                    cth[p2] = __cosf(th); sth[p2] = __sinf(th);
                }
#pragma unroll
                for (int j = 0; j < 4; j++) {
                    int kcol = n0 - 1024 + wc * 64 + j * 16 + cc;
                    int h = kcol >> 6, dd2 = kcol & 63;          // dd2 = j*16+cc
                    float sgn = (j < 2) ? -1.0f : 1.0f;          // d < 32
                    float v = acc[i][j][r], p = acc[i][j ^ 2][r];   // partner d^32
                    Km[((size_t)(bb * 16 + h) * 2048 + n) * 64 + dd2] =
                        f2bf(v * cth[j & 1] + sgn * p * sth[j & 1]);
                }
            }
    } else {
#pragma unroll
        for (int i = 0; i < 4; i++)
#pragma unroll
            for (int j = 0; j < 4; j++)
#pragma unroll
                for (int r = 0; r < 4; r++) {
                    int row = m0 + wr * 64 + i * 16 + qd * 4 + r;
                    int col = n0 + wc * 64 + j * 16 + cc;
                    C[(size_t)row * N + col] = f2bf(acc[i][j][r]);
                }
    }
}

// ---------------------------------------------------------------------------
// v_scatter (R19: V only — K roped in gemm_bt, Q roped in flash):
// qkv V-slice -> Vt[B,H,D,N] transposed, masked-key rows zeroed, key axis
// perm16-permuted within each 16-key block.  No trig.
// ---------------------------------------------------------------------------
__global__ __launch_bounds__(256) void v_scatter(const unsigned short* __restrict__ qkv,
                                                 const int* __restrict__ msk,
                                                 unsigned short* __restrict__ Vt) {
    const int N = 2048, H = 16, D = 64, C3 = 3072;
    __shared__ unsigned short vl[64][65];       // +1 pad for transpose reads
    const int nt = blockIdx.x, h = blockIdx.y, b = blockIdx.z;
    const int n0 = nt * 64;
    const int tid = threadIdx.x;
    const size_t bh = (size_t)b * H + h;
#pragma unroll
    for (int it = 0; it < 2; it++) {
        int idx = tid + it * 256;           // 0..511
        int row = idx >> 3, seg = idx & 7;
        int d0 = seg * 8;
        int n = n0 + row;
        int keep = msk[(size_t)b * N + n];
        u16x8 vv = *(const u16x8*)&qkv[((size_t)b * N + n) * C3 + 2048 + h * 64 + d0];
#pragma unroll
        for (int j = 0; j < 8; j++) vl[row][d0 + j] = keep ? vv[j] : (unsigned short)0;
    }
    __syncthreads();
    // transposed V write: Vt[b,h,d, n-permuted]: Vt[.., 16t+p] = V[16t+perm16(p)]
#pragma unroll
    for (int it = 0; it < 2; it++) {
        int idx = tid + it * 256;
        int drow = idx >> 3, nseg = idx & 7;
        u16x8 ov;
#pragma unroll
        for (int j = 0; j < 8; j++) {
            int cpos = nseg * 8 + j;
            int srcl = (cpos & ~15) | perm16(cpos & 15);
            ov[j] = vl[srcl][drow];
        }
        *(u16x8*)&Vt[(bh * D + drow) * N + n0 + nseg * 8] = ov;
    }
}

// ---------------------------------------------------------------------------
// Flash attention (R15 structure + R18 in-register Q-RoPE): 32x32x16 MFMA,
// key-split waves (qhalf = wave&1, khalf = wave>>1): each wave computes
// 64 q-rows x its 32-key half of every 64-key tile.  Raw Q read from qkv;
// RoPE applied thread-locally (partner d^32 = qraw[kd^2], jj=(kd&1)*16+
// hi*8+j, sgn=kd<2?-1:+1) with SCL folded in.  In-register P (R11 perm16),
// LDS-staged double-buffered K/V, XCD swizzle (512 = 8 x 64), cross-wave
// o/lacc reduction via LDS.
// ---------------------------------------------------------------------------
__global__ __launch_bounds__(256, 2) void flash_attn(const unsigned short* __restrict__ qkvp,
                                                     const unsigned short* __restrict__ Kg,
                                                     const unsigned short* __restrict__ Vt,
                                                     const unsigned short* __restrict__ mb,
                                                     unsigned short* __restrict__ Og) {
    const int N = 2048, H = 16, D = 64;
    const float SCL = 0.18033688f;              // 0.125 * log2(e)
    __shared__ unsigned short ldsbuf[4 * 64 * 64];   // 32KB: K0,K1,V0,V1 / reduction
    unsigned short (*Kl0)[64] = (unsigned short(*)[64])(ldsbuf);
    unsigned short (*Kl1)[64] = (unsigned short(*)[64])(ldsbuf + 4096);
    unsigned short (*Vl0)[64] = (unsigned short(*)[64])(ldsbuf + 8192);
    unsigned short (*Vl1)[64] = (unsigned short(*)[64])(ldsbuf + 12288);
    const int tid  = threadIdx.x;
    const int lane = tid & 63;
    const int wave = tid >> 6;                 // 0..3
    const int qhalf = wave & 1;                // q-rows [qhalf*64, +64)
    const int khalf = wave >> 1;               // keys [khalf*32, +32) of each tile
    const int c    = lane & 31;
    const int hi   = lane >> 5;
    // XCD swizzle: 512 blocks = 8 XCDs x 64; each XCD gets 4 (b,h) pairs
    int dd = blockIdx.x;
    int sw = (dd & 7) * 64 + (dd >> 3);
    const int qt = sw & 15, h = (sw >> 4) & 15, b = sw >> 8;
    const int q0 = qt * 128;
    const size_t bh = (size_t)b * H + h;

    // Q B-frags with in-register RoPE (B[n=q=lane&31][k=d=kd*16+hi*8+j]):
    s16x8 qf[2][4];
    {
        s16x8 qraw[2][4];
#pragma unroll
        for (int qs = 0; qs < 2; qs++) {
            const unsigned short* Qb =
                qkvp + ((size_t)b * N + q0 + qhalf * 64 + qs * 32 + c) * 3072 + h * 64;
#pragma unroll
            for (int kd = 0; kd < 4; kd++)
                qraw[qs][kd] = *(const s16x8*)(Qb + kd * 16 + hi * 8);
        }
#pragma unroll
        for (int qs = 0; qs < 2; qs++) {
            float nn = (float)(q0 + qhalf * 64 + qs * 32 + c);
#pragma unroll
            for (int kd = 0; kd < 4; kd++) {
                float sgn = (kd < 2) ? -1.0f : 1.0f;     // rotate_half sign (d<32)
#pragma unroll
                for (int j = 0; j < 8; j++) {
                    int jj = (kd & 1) * 16 + hi * 8 + j;               // d & 31
                    float th = nn * exp2f(-0.34375f * (float)jj);
                    float cth = __cosf(th), sth = __sinf(th);
                    float v = bf2f((unsigned short)qraw[qs][kd][j]);
                    float p = bf2f((unsigned short)qraw[qs][kd ^ 2][j]); // d ^ 32
                    qf[qs][kd][j] = (short)f2bf((v * cth + sgn * p * sth) * SCL);
                }
            }
        }
    }

    f32x16 o[2][2], lacc[2];
#pragma unroll
    for (int qs = 0; qs < 2; qs++) {
        o[qs][0] = zero16(); o[qs][1] = zero16(); lacc[qs] = zero16();
    }

    const unsigned short* Kbase = Kg + bh * N * D;
    const unsigned short* Vbase = Vt + bh * D * N;
    const unsigned short* mbase = mb + (size_t)b * N;   // perm16'd bf16 0/1 mask
    const int row_s = tid >> 3, sg_s = (tid & 7) ^ ((tid >> 3) & 7);
    const int row_s2 = (tid + 256) >> 3, sg_s2 = (tid & 7) ^ (((tid + 256) >> 3) & 7);

    auto issue = [&](int k0, unsigned short* Kb, unsigned short* Vb) {
        GLD_TO_LDS(Kbase + (size_t)(k0 + row_s) * D + sg_s * 8,   Kb + tid * 8);
        GLD_TO_LDS(Vbase + (size_t)row_s * N + k0 + sg_s * 8,     Vb + tid * 8);
        GLD_TO_LDS(Kbase + (size_t)(k0 + row_s2) * D + sg_s2 * 8, Kb + (tid + 256) * 8);
        GLD_TO_LDS(Vbase + (size_t)row_s2 * N + k0 + sg_s2 * 8,   Vb + (tid + 256) * 8);
    };

    auto compute = [&](int k0, const unsigned short (*Kb)[64], const unsigned short (*Vb)[64]) {
        // exp2 + DIRECT in-register pack (R11 layout: keys perm16'd in V/mask)
        auto packkg = [&](const f32x16& sstv, s16x8* pa) {
            float p[16];
#pragma unroll
            for (int r = 0; r < 16; r++) p[r] = __builtin_amdgcn_exp2f(sstv[r]);
#pragma unroll
            for (int half = 0; half < 2; half++) {
                int bs = half * 8;
                u32x4 w = { pkbf(p[bs + 0], p[bs + 1]), pkbf(p[bs + 2], p[bs + 3]),
                            pkbf(p[bs + 4], p[bs + 5]), pkbf(p[bs + 6], p[bs + 7]) };
                pa[half] = __builtin_bit_cast(s16x8, w);
            }
        };

        // ---- QK^T on this wave's 32-key half, both q-sub-blocks ----------
        int kr = khalf * 32 + c;
        s16x8 kf[4];
#pragma unroll
        for (int kd = 0; kd < 4; kd++)
            kf[kd] = *(const s16x8*)&Kb[kr][((kd * 2 + hi) ^ (kr & 7)) * 8];
        f32x16 sst0 = zero16(), sst1 = zero16();
        __builtin_amdgcn_s_setprio(1);
#pragma unroll
        for (int kd = 0; kd < 4; kd++) {
            sst0 = MFMA32_BF16(kf[kd], qf[0][kd], sst0);
            sst1 = MFMA32_BF16(kf[kd], qf[1][kd], sst1);
        }
        __builtin_amdgcn_s_setprio(0);
        s16x8 pa[2][2];                    // [qs][ksl]
        packkg(sst0, pa[0]);
        packkg(sst1, pa[1]);

        // ---- O += P V ; l += P @ mask on the wave's two 16-key slices ----
#pragma unroll
        for (int ksl = 0; ksl < 2; ksl++) {
            int ks = khalf * 2 + ksl;      // global 16-key slice
            s16x8 mfr = *(const s16x8*)&mbase[k0 + ks * 16 + hi * 8];
            int vr0 = c, vr1 = 32 + c;
            s16x8 vf0 = *(const s16x8*)&Vb[vr0][((ks * 2 + hi) ^ (vr0 & 7)) * 8];
            s16x8 vf1 = *(const s16x8*)&Vb[vr1][((ks * 2 + hi) ^ (vr1 & 7)) * 8];
            __builtin_amdgcn_s_setprio(1);
#pragma unroll
            for (int qs = 0; qs < 2; qs++) {
                lacc[qs]  = MFMA32_BF16(pa[qs][ksl], mfr, lacc[qs]);
                o[qs][0]  = MFMA32_BF16(pa[qs][ksl], vf0, o[qs][0]);
                o[qs][1]  = MFMA32_BF16(pa[qs][ksl], vf1, o[qs][1]);
            }
            __builtin_amdgcn_s_setprio(0);
        }
    };

    issue(0, &Kl0[0][0], &Vl0[0][0]);
    __syncthreads();
    for (int it = 0; it < 32; it += 2) {
        int k0 = it * 64;
        if (it + 1 < 32) issue(k0 + 64, &Kl1[0][0], &Vl1[0][0]);
        compute(k0, Kl0, Vl0);
        __syncthreads();
        if (it + 2 < 32) issue(k0 + 128, &Kl0[0][0], &Vl0[0][0]);
        compute(k0 + 64, Kl1, Vl1);
        __syncthreads();
    }

    // ---- cross-wave reduction: khalf=1 partials -> khalf=0 ---------------
    // stride 49 floats/lane -> bank (lane*17 + r) % 32, conflict-free.
    float* red = (float*)ldsbuf;
#pragma unroll
    for (int qs = 0; qs < 2; qs++) {
        __syncthreads();
        if (khalf == 1) {
            float* dst = red + qhalf * 3136 + lane * 49;
#pragma unroll
            for (int r = 0; r < 16; r++) {
                dst[r] = o[qs][0][r]; dst[16 + r] = o[qs][1][r]; dst[32 + r] = lacc[qs][r];
            }
        }
        __syncthreads();
        if (khalf == 0) {
            const float* src = red + qhalf * 3136 + lane * 49;
#pragma unroll
            for (int r = 0; r < 16; r++) {
                o[qs][0][r] += src[r]; o[qs][1][r] += src[16 + r]; lacc[qs][r] += src[32 + r];
            }
        }
    }

    // epilogue (khalf==0 waves): row q = q0+qhalf*64+qs*32+(r&3)+8(r>>2)+4hi
    if (khalf == 0) {
#pragma unroll
        for (int qs = 0; qs < 2; qs++) {
            float linv[16];
#pragma unroll
            for (int r = 0; r < 16; r++) linv[r] = 1.0f / lacc[qs][r];
#pragma unroll
            for (int db = 0; db < 2; db++)
#pragma unroll
                for (int r = 0; r < 16; r++) {
                    int n = q0 + qhalf * 64 + qs * 32 + (r & 3) + 8 * (r >> 2) + 4 * hi;
                    Og[((size_t)b * N + n) * 1024 + h * 64 + db * 32 + c] =
                        f2bf(o[qs][db][r] * linv[r]);
                }
        }
    }
}

// ---------------------------------------------------------------------------
// Projection GEMM: out[4096,1024] = attno[4096,1024] @ w_proj^T + bias, fp32.
// 1D grid (512 = 8 x 64), XCD-chunked swizzle.
// ---------------------------------------------------------------------------
__global__ __launch_bounds__(256) void gemm_proj(const unsigned short* __restrict__ A,
                                                 const unsigned short* __restrict__ B,
                                                 float* __restrict__ C,
                                                 const float* __restrict__ bias) {
    const int NN = 1024, K = 1024;
    __shared__ unsigned short Al[128][64];
    __shared__ unsigned short Bl[64][64];
    const int tid  = threadIdx.x;
    const int lane = tid & 63;
    const int qd   = lane >> 4;
    const int cc   = lane & 15;
    const int wave = tid >> 6;
    const int wr   = wave >> 1, wc = wave & 1;
    int dd = blockIdx.x;                        // 512 = 8 x 64
    int sw = (dd & 7) * 64 + (dd >> 3);
    const int m0   = (sw >> 4) * 128, n0 = (sw & 15) * 64;
    unsigned short* Alf = &Al[0][0];
    unsigned short* Blf = &Bl[0][0];

    f32x4 acc[4][2];
#pragma unroll
    for (int i = 0; i < 4; i++)
#pragma unroll
        for (int j = 0; j < 2; j++) acc[i][j] = (f32x4){0.f, 0.f, 0.f, 0.f};

    for (int k0 = 0; k0 < K; k0 += 64) {
#pragma unroll
        for (int t = 0; t < 4; t++) {
            int idx = t * 256 + tid;
            int row = idx >> 3, sg = (idx & 7) ^ (row & 7);
            GLD_TO_LDS(A + (size_t)(m0 + row) * K + k0 + sg * 8, Alf + idx * 8);
        }
#pragma unroll
        for (int t = 0; t < 2; t++) {
            int idx = t * 256 + tid;
            int row = idx >> 3, sg = (idx & 7) ^ (row & 7);
            GLD_TO_LDS(B + (size_t)(n0 + row) * K + k0 + sg * 8, Blf + idx * 8);
        }
        __syncthreads();
#pragma unroll
        for (int ks = 0; ks < 64; ks += 32) {
            const int s4 = ks >> 3;
            s16x8 af[4], bf[2];
#pragma unroll
            for (int i = 0; i < 4; i++) {
                int r = wr * 64 + i * 16 + cc;
                af[i] = *(const s16x8*)&Al[r][((s4 + qd) ^ (r & 7)) * 8];
            }
#pragma unroll
            for (int j = 0; j < 2; j++) {
                int r = wc * 32 + j * 16 + cc;
                bf[j] = *(const s16x8*)&Bl[r][((s4 + qd) ^ (r & 7)) * 8];
            }
#pragma unroll
            for (int i = 0; i < 4; i++)
#pragma unroll
                for (int j = 0; j < 2; j++)
                    acc[i][j] = MFMA_BF16(af[i], bf[j], acc[i][j]);
        }
        __syncthreads();
    }
#pragma unroll
    for (int i = 0; i < 4; i++)
#pragma unroll
        for (int j = 0; j < 2; j++)
#pragma unroll
            for (int r = 0; r < 4; r++) {
                int row = m0 + wr * 64 + i * 16 + qd * 4 + r;
                int col = n0 + wc * 32 + j * 16 + cc;
                C[(size_t)row * NN + col] = acc[i][j][r] + bias[col];
            }
}

// ---------------------------------------------------------------------------
extern "C" void kernel_launch(void* const* d_in, const int* in_sizes, int n_in,
                              void* d_out, int out_size, void* d_ws, size_t ws_size,
                              hipStream_t stream) {
    const float* x      = (const float*)d_in[0];
    const float* w_qkv  = (const float*)d_in[1];
    const float* w_proj = (const float*)d_in[2];
    const float* b_proj = (const float*)d_in[3];
    const int*   mask   = (const int*)d_in[4];
    float* out = (float*)d_out;

    // workspace layout (bf16 elements), ~72 MB
    unsigned short* ws     = (unsigned short*)d_ws;
    unsigned short* xb     = ws;                                  // 4096*1024
    unsigned short* wqkvb  = xb     + (size_t)4096 * 1024;        // 3072*1024
    unsigned short* wprojb = wqkvb  + (size_t)3072 * 1024;        // 1024*1024
    unsigned short* qkv    = wprojb + (size_t)1024 * 1024;        // 4096*3072
    unsigned short* Qm     = qkv    + (size_t)4096 * 3072;        // unused (R18)
    unsigned short* Km     = Qm     + (size_t)32 * 2048 * 64;
    unsigned short* Vtm    = Km     + (size_t)32 * 2048 * 64;
    unsigned short* attno  = Vtm    + (size_t)32 * 2048 * 64;     // 4096*1024
    unsigned short* maskbf = attno  + (size_t)4096 * 1024;        // 2*2048 bf16

    // converts (32B/thread) + perm16'd bf16 mask vector, one launch
    prep<<<4112, 256, 0, stream>>>(x, w_qkv, w_proj, mask, xb, wqkvb, wprojb, maskbf);
    // qkv = x @ w_qkv^T; K-region tiles rope in-epilogue -> Km directly
    gemm_bt<<<768, 256, 0, stream>>>(xb, wqkvb, qkv, Km, 4096, 3072, 1024);
    // V scatter: Vt [B,H,D,N] perm16'd + masked rows zeroed (no trig)
    v_scatter<<<dim3(32, 16, 2), 256, 0, stream>>>(qkv, mask, Vtm);
    // attention: 128-row Q tiles, key-split waves, 32x32 MFMA, in-reg P,
    // in-reg Q-RoPE from qkv, LDS-staged K/V  (512 blocks = 8 x 64, XCD-swizzled)
    flash_attn<<<512, 256, 0, stream>>>(qkv, Km, Vtm, maskbf, attno);
    // out = attn_out @ w_proj^T + b_proj   (512 blocks = 8 x 64, XCD-swizzled)
    gemm_proj<<<512, 256, 0, stream>>>(attno, wprojb, out, b_proj);
}

// Round 15
// 176.824 us; speedup vs baseline: 1.0381x; 1.0127x over previous
//
#include <hip/hip_runtime.h>

// ---------------------------------------------------------------------------
// Fused attention: x@Wqkv^T -> RoPE -> masked softmax attention -> @Wproj^T+b
// B=2, N=2048, C=1024, H=16, D=64.  All MFMA compute in bf16, fp32 accum.
//
// LESSON (R5): no scalar 2B global stores — dense u16x8 runs only.
// LESSON (R10): unverified cross-lane primitives scramble layouts; use
// perm16 pre-permuted V/mask instead (R11, verified).
// LESSON (R13): LDS staging is a COALESCING transform, not just a cache.
// LESSON (R14/R15): flash is sum-of-pipes bound at ~51 us.  Parked.
// LESSON (R16): verify grid arithmetic before theorizing.
// LESSON (R18): e2e noise is +-2-4 us; per-kernel dur is the reliable signal.
// R17 (WIN 179.9): prep 32B/thread + fast trig.
// R18/R19 (WIN 179.1, absmax 0.00195): Q-RoPE into flash, K-RoPE into
// gemm_bt epilogue (same-lane j^2 partner trick, fp32-accurate).
//
// R20: V fused into gemm_bt epilogue too.  V-region tiles (n0 in
// [2048,3072)) stage mask-zeroed bf16 accums into LDS [128][stride 130],
// then write Vt[b,h,d,n] via the v_scatter transpose+perm16 pattern (dense
// u16x8).  v_scatter DELETED (-8MB read, -8MB write, -1 launch); qkv V
// region never written.
// ---------------------------------------------------------------------------

typedef __attribute__((ext_vector_type(8))) short          s16x8;
typedef __attribute__((ext_vector_type(8))) unsigned short u16x8;
typedef __attribute__((ext_vector_type(4))) unsigned short u16x4;
typedef __attribute__((ext_vector_type(4))) float          f32x4;
typedef __attribute__((ext_vector_type(16))) float         f32x16;
typedef __attribute__((ext_vector_type(4))) unsigned int   u32x4;

#define MFMA_BF16(a, b, c) __builtin_amdgcn_mfma_f32_16x16x32_bf16((a), (b), (c), 0, 0, 0)
#define MFMA32_BF16(a, b, c) __builtin_amdgcn_mfma_f32_32x32x16_bf16((a), (b), (c), 0, 0, 0)

// async global->LDS, 16B per lane (dest = wave-uniform base + lane*16)
#define GLD_TO_LDS(gp, lp) __builtin_amdgcn_global_load_lds(                  \
    (const __attribute__((address_space(1))) void*)(gp),                      \
    (__attribute__((address_space(3))) void*)(lp), 16, 0, 0)

__device__ __forceinline__ unsigned short f2bf(float f) {
    union { float f; unsigned int u; } v; v.f = f;
    unsigned int u = v.u;
    unsigned int r = u + 0x7FFFu + ((u >> 16) & 1u);   // round-to-nearest-even
    return (unsigned short)(r >> 16);
}
__device__ __forceinline__ float bf2f(unsigned short h) {
    union { unsigned int u; float f; } v; v.u = ((unsigned int)h) << 16;
    return v.f;
}
__device__ __forceinline__ f32x16 zero16() {
    f32x16 z;
#pragma unroll
    for (int i = 0; i < 16; i++) z[i] = 0.f;
    return z;
}
// pack two f32 -> one u32 of 2 bf16 (truncating): low half = a, high = b
__device__ __forceinline__ unsigned int pkbf(float a, float b) {
    return __builtin_amdgcn_perm(__builtin_bit_cast(unsigned int, b),
                                 __builtin_bit_cast(unsigned int, a), 0x07060302u);
}
// key permutation within a 16-block matching the 32x32 C/D row map
// (involution: swaps 4..7 <-> 8..11)
__device__ __forceinline__ int perm16(int p) {
    return (p & 3) + 8 * ((p >> 2) & 1) + 4 * (p >> 3);
}

// ---------------------------------------------------------------------------
// prep: fp32->bf16 converts (32B/thread) + mask -> perm16'd bf16 0/1 vector.
// Blocks: [0,2048) x, [2048,3584) w_qkv, [3584,4096) w_proj, [4096,4112) mask.
// ---------------------------------------------------------------------------
__global__ __launch_bounds__(256) void prep(const float* __restrict__ x,
                                            const float* __restrict__ wqkv,
                                            const float* __restrict__ wproj,
                                            const int* __restrict__ m,
                                            unsigned short* __restrict__ xb,
                                            unsigned short* __restrict__ wqkvb,
                                            unsigned short* __restrict__ wprojb,
                                            unsigned short* __restrict__ mb) {
    int blk = blockIdx.x, tid = threadIdx.x;
    if (blk < 4096) {
        const float* src; unsigned short* dst; int i;
        if (blk < 2048)      { src = x;     dst = xb;     i = blk * 256 + tid; }
        else if (blk < 3584) { src = wqkv;  dst = wqkvb;  i = (blk - 2048) * 256 + tid; }
        else                 { src = wproj; dst = wprojb; i = (blk - 3584) * 256 + tid; }
        f32x4 v0 = ((const f32x4*)src)[i * 2];
        f32x4 v1 = ((const f32x4*)src)[i * 2 + 1];
        u16x8 o;
        o[0] = f2bf(v0[0]); o[1] = f2bf(v0[1]); o[2] = f2bf(v0[2]); o[3] = f2bf(v0[3]);
        o[4] = f2bf(v1[0]); o[5] = f2bf(v1[1]); o[6] = f2bf(v1[2]); o[7] = f2bf(v1[3]);
        ((u16x8*)dst)[i] = o;
    } else {
        int i = (blk - 4096) * 256 + tid;
        int src = (i & ~15) | perm16(i & 15);          // N=2048 % 16 == 0: stays in batch
        mb[i] = (m[src] == 0) ? (unsigned short)0 : (unsigned short)0x3F80;  // bf16 1.0
    }
}

// ---------------------------------------------------------------------------
// bf16 GEMM, C[M,N] = A[M,K] * B[N,K]^T.  128x128 tile, BK=64, 768 blocks.
// Epilogues by N-region:
//   [0,1024)    Q: bf16 -> qkv (flash ropes Q in-register from there)
//   [1024,2048) K: in-register RoPE (partner d^32 = acc[i][j^2][r]) -> Km
//   [2048,3072) V: mask-zero bf16 -> LDS [128][130] -> transpose + perm16
//               -> Vt[b,h,d,n] dense u16x8 (the v_scatter pattern, fused).
// XCD-chunked swizzle.
// ---------------------------------------------------------------------------
__global__ __launch_bounds__(256) void gemm_bt(const unsigned short* __restrict__ A,
                                               const unsigned short* __restrict__ B,
                                               const int* __restrict__ msk,
                                               unsigned short* __restrict__ C,
                                               unsigned short* __restrict__ Km,
                                               unsigned short* __restrict__ Vt,
                                               int M, int N, int K) {
    __shared__ unsigned short sbuf[128 * 130];   // Al/Bl alias + V-transpose buffer
    unsigned short (*Al)[64] = (unsigned short(*)[64])(sbuf);
    unsigned short (*Bl)[64] = (unsigned short(*)[64])(sbuf + 128 * 64);
    const int tid  = threadIdx.x;
    const int lane = tid & 63;
    const int qd   = lane >> 4;     // quad 0..3
    const int cc   = lane & 15;
    const int wave = tid >> 6;
    const int wr   = wave >> 1, wc = wave & 1;
    // XCD swizzle: chunk the grid so consecutive M-panels share an XCD L2
    const int nbx  = N >> 7;                     // N-tiles
    const int nwg  = gridDim.x;
    int d = blockIdx.x;
    int s = (nwg % 8 == 0) ? (d % 8) * (nwg / 8) + d / 8 : d;
    const int m0   = (s / nbx) * 128, n0 = (s % nbx) * 128;
    unsigned short* Alf = &Al[0][0];
    unsigned short* Blf = &Bl[0][0];

    f32x4 acc[4][4];
#pragma unroll
    for (int i = 0; i < 4; i++)
#pragma unroll
        for (int j = 0; j < 4; j++) acc[i][j] = (f32x4){0.f, 0.f, 0.f, 0.f};

    for (int k0 = 0; k0 < K; k0 += 64) {
#pragma unroll
        for (int t = 0; t < 4; t++) {
            int idx = t * 256 + tid;                 // 0..1023
            int row = idx >> 3, sg = (idx & 7) ^ (row & 7);
            GLD_TO_LDS(A + (size_t)(m0 + row) * K + k0 + sg * 8, Alf + idx * 8);
            GLD_TO_LDS(B + (size_t)(n0 + row) * K + k0 + sg * 8, Blf + idx * 8);
        }
        __syncthreads();
#pragma unroll
        for (int ks = 0; ks < 64; ks += 32) {
            const int s4 = ks >> 3;                  // 0 or 4
            s16x8 af[4], bf[4];
#pragma unroll
            for (int i = 0; i < 4; i++) {
                int r = wr * 64 + i * 16 + cc;
                af[i] = *(const s16x8*)&Al[r][((s4 + qd) ^ (r & 7)) * 8];
            }
#pragma unroll
            for (int j = 0; j < 4; j++) {
                int r = wc * 64 + j * 16 + cc;
                bf[j] = *(const s16x8*)&Bl[r][((s4 + qd) ^ (r & 7)) * 8];
            }
#pragma unroll
            for (int i = 0; i < 4; i++)
#pragma unroll
                for (int j = 0; j < 4; j++)
                    acc[i][j] = MFMA_BF16(af[i], bf[j], acc[i][j]);
        }
        __syncthreads();
    }
    // epilogue: C/D layout col=lane&15, row=quad*4+reg
    if (n0 >= 2048) {
        // ---- V region: mask-zero, stage to LDS, transpose+perm16 -> Vt ---
        // (last K-iter barrier ordered all LDS reads before this overwrite)
        const int bb = m0 >> 11, tok0 = m0 & 2047;
#pragma unroll
        for (int i = 0; i < 4; i++)
#pragma unroll
            for (int r = 0; r < 4; r++) {
                int tl = wr * 64 + i * 16 + qd * 4 + r;          // token-local
                int keep = msk[(size_t)bb * 2048 + tok0 + tl];
#pragma unroll
                for (int j = 0; j < 4; j++) {
                    int cl = wc * 64 + j * 16 + cc;              // col-local
                    sbuf[tl * 130 + cl] = keep ? f2bf(acc[i][j][r]) : (unsigned short)0;
                }
            }
        __syncthreads();
        // write: 128 d-rows x 16 token-segments, dense u16x8 (v_scatter pattern)
#pragma unroll
        for (int it = 0; it < 8; it++) {
            int idx = it * 256 + tid;        // 0..2047
            int dr = idx >> 4, seg = idx & 15;
            int col = n0 - 2048 + dr;        // global V column
            int gh = col >> 6, dd2 = col & 63;
            u16x8 ov;
#pragma unroll
            for (int j = 0; j < 8; j++) {
                int cpos = seg * 8 + j;
                int srcl = (cpos & ~15) | perm16(cpos & 15);
                ov[j] = sbuf[srcl * 130 + dr];
            }
            *(u16x8*)&Vt[((size_t)(bb * 16 + gh) * 64 + dd2) * 2048 + tok0 + seg * 8] = ov;
        }
    } else if (n0 >= 1024) {
        // ---- K region: in-register RoPE (from fp32 acc), write Km --------
#pragma unroll
        for (int i = 0; i < 4; i++)
#pragma unroll
            for (int r = 0; r < 4; r++) {
                int row = m0 + wr * 64 + i * 16 + qd * 4 + r;   // token index
                int bb = row >> 11, n = row & 2047;
                float cth[2], sth[2];
#pragma unroll
                for (int p2 = 0; p2 < 2; p2++) {
                    float th = (float)n * exp2f(-0.34375f * (float)(p2 * 16 + cc));
                    cth[p2] = __cosf(th); sth[p2] = __sinf(th);
                }
#pragma unroll
                for (int j = 0; j < 4; j++) {
                    int kcol = n0 - 1024 + wc * 64 + j * 16 + cc;
                    int h = kcol >> 6, dd2 = kcol & 63;          // dd2 = j*16+cc
                    float sgn = (j < 2) ? -1.0f : 1.0f;          // d < 32
                    float v = acc[i][j][r], p = acc[i][j ^ 2][r];   // partner d^32
                    Km[((size_t)(bb * 16 + h) * 2048 + n) * 64 + dd2] =
                        f2bf(v * cth[j & 1] + sgn * p * sth[j & 1]);
                }
            }
    } else {
        // ---- Q region: bf16 -> qkv (flash ropes it in-register) ----------
#pragma unroll
        for (int i = 0; i < 4; i++)
#pragma unroll
            for (int j = 0; j < 4; j++)
#pragma unroll
                for (int r = 0; r < 4; r++) {
                    int row = m0 + wr * 64 + i * 16 + qd * 4 + r;
                    int col = n0 + wc * 64 + j * 16 + cc;
                    C[(size_t)row * N + col] = f2bf(acc[i][j][r]);
                }
    }
}

// ---------------------------------------------------------------------------
// Flash attention (R15 structure + R18 in-register Q-RoPE): 32x32x16 MFMA,
// key-split waves (qhalf = wave&1, khalf = wave>>1): each wave computes
// 64 q-rows x its 32-key half of every 64-key tile.  Raw Q read from qkv;
// RoPE applied thread-locally (partner d^32 = qraw[kd^2], jj=(kd&1)*16+
// hi*8+j, sgn=kd<2?-1:+1) with SCL folded in.  In-register P (R11 perm16),
// LDS-staged double-buffered K/V, XCD swizzle (512 = 8 x 64), cross-wave
// o/lacc reduction via LDS.
// ---------------------------------------------------------------------------
__global__ __launch_bounds__(256, 2) void flash_attn(const unsigned short* __restrict__ qkvp,
                                                     const unsigned short* __restrict__ Kg,
                                                     const unsigned short* __restrict__ Vt,
                                                     const unsigned short* __restrict__ mb,
                                                     unsigned short* __restrict__ Og) {
    const int N = 2048, H = 16, D = 64;
    const float SCL = 0.18033688f;              // 0.125 * log2(e)
    __shared__ unsigned short ldsbuf[4 * 64 * 64];   // 32KB: K0,K1,V0,V1 / reduction
    unsigned short (*Kl0)[64] = (unsigned short(*)[64])(ldsbuf);
    unsigned short (*Kl1)[64] = (unsigned short(*)[64])(ldsbuf + 4096);
    unsigned short (*Vl0)[64] = (unsigned short(*)[64])(ldsbuf + 8192);
    unsigned short (*Vl1)[64] = (unsigned short(*)[64])(ldsbuf + 12288);
    const int tid  = threadIdx.x;
    const int lane = tid & 63;
    const int wave = tid >> 6;                 // 0..3
    const int qhalf = wave & 1;                // q-rows [qhalf*64, +64)
    const int khalf = wave >> 1;               // keys [khalf*32, +32) of each tile
    const int c    = lane & 31;
    const int hi   = lane >> 5;
    // XCD swizzle: 512 blocks = 8 XCDs x 64; each XCD gets 4 (b,h) pairs
    int dd = blockIdx.x;
    int sw = (dd & 7) * 64 + (dd >> 3);
    const int qt = sw & 15, h = (sw >> 4) & 15, b = sw >> 8;
    const int q0 = qt * 128;
    const size_t bh = (size_t)b * H + h;

    // Q B-frags with in-register RoPE (B[n=q=lane&31][k=d=kd*16+hi*8+j]):
    s16x8 qf[2][4];
    {
        s16x8 qraw[2][4];
#pragma unroll
        for (int qs = 0; qs < 2; qs++) {
            const unsigned short* Qb =
                qkvp + ((size_t)b * N + q0 + qhalf * 64 + qs * 32 + c) * 3072 + h * 64;
#pragma unroll
            for (int kd = 0; kd < 4; kd++)
                qraw[qs][kd] = *(const s16x8*)(Qb + kd * 16 + hi * 8);
        }
#pragma unroll
        for (int qs = 0; qs < 2; qs++) {
            float nn = (float)(q0 + qhalf * 64 + qs * 32 + c);
#pragma unroll
            for (int kd = 0; kd < 4; kd++) {
                float sgn = (kd < 2) ? -1.0f : 1.0f;     // rotate_half sign (d<32)
#pragma unroll
                for (int j = 0; j < 8; j++) {
                    int jj = (kd & 1) * 16 + hi * 8 + j;               // d & 31
                    float th = nn * exp2f(-0.34375f * (float)jj);
                    float cth = __cosf(th), sth = __sinf(th);
                    float v = bf2f((unsigned short)qraw[qs][kd][j]);
                    float p = bf2f((unsigned short)qraw[qs][kd ^ 2][j]); // d ^ 32
                    qf[qs][kd][j] = (short)f2bf((v * cth + sgn * p * sth) * SCL);
                }
            }
        }
    }

    f32x16 o[2][2], lacc[2];
#pragma unroll
    for (int qs = 0; qs < 2; qs++) {
        o[qs][0] = zero16(); o[qs][1] = zero16(); lacc[qs] = zero16();
    }

    const unsigned short* Kbase = Kg + bh * N * D;
    const unsigned short* Vbase = Vt + bh * D * N;
    const unsigned short* mbase = mb + (size_t)b * N;   // perm16'd bf16 0/1 mask
    const int row_s = tid >> 3, sg_s = (tid & 7) ^ ((tid >> 3) & 7);
    const int row_s2 = (tid + 256) >> 3, sg_s2 = (tid & 7) ^ (((tid + 256) >> 3) & 7);

    auto issue = [&](int k0, unsigned short* Kb, unsigned short* Vb) {
        GLD_TO_LDS(Kbase + (size_t)(k0 + row_s) * D + sg_s * 8,   Kb + tid * 8);
        GLD_TO_LDS(Vbase + (size_t)row_s * N + k0 + sg_s * 8,     Vb + tid * 8);
        GLD_TO_LDS(Kbase + (size_t)(k0 + row_s2) * D + sg_s2 * 8, Kb + (tid + 256) * 8);
        GLD_TO_LDS(Vbase + (size_t)row_s2 * N + k0 + sg_s2 * 8,   Vb + (tid + 256) * 8);
    };

    auto compute = [&](int k0, const unsigned short (*Kb)[64], const unsigned short (*Vb)[64]) {
        // exp2 + DIRECT in-register pack (R11 layout: keys perm16'd in V/mask)
        auto packkg = [&](const f32x16& sstv, s16x8* pa) {
            float p[16];
#pragma unroll
            for (int r = 0; r < 16; r++) p[r] = __builtin_amdgcn_exp2f(sstv[r]);
#pragma unroll
            for (int half = 0; half < 2; half++) {
                int bs = half * 8;
                u32x4 w = { pkbf(p[bs + 0], p[bs + 1]), pkbf(p[bs + 2], p[bs + 3]),
                            pkbf(p[bs + 4], p[bs + 5]), pkbf(p[bs + 6], p[bs + 7]) };
                pa[half] = __builtin_bit_cast(s16x8, w);
            }
        };

        // ---- QK^T on this wave's 32-key half, both q-sub-blocks ----------
        int kr = khalf * 32 + c;
        s16x8 kf[4];
#pragma unroll
        for (int kd = 0; kd < 4; kd++)
            kf[kd] = *(const s16x8*)&Kb[kr][((kd * 2 + hi) ^ (kr & 7)) * 8];
        f32x16 sst0 = zero16(), sst1 = zero16();
        __builtin_amdgcn_s_setprio(1);
#pragma unroll
        for (int kd = 0; kd < 4; kd++) {
            sst0 = MFMA32_BF16(kf[kd], qf[0][kd], sst0);
            sst1 = MFMA32_BF16(kf[kd], qf[1][kd], sst1);
        }
        __builtin_amdgcn_s_setprio(0);
        s16x8 pa[2][2];                    // [qs][ksl]
        packkg(sst0, pa[0]);
        packkg(sst1, pa[1]);

        // ---- O += P V ; l += P @ mask on the wave's two 16-key slices ----
#pragma unroll
        for (int ksl = 0; ksl < 2; ksl++) {
            int ks = khalf * 2 + ksl;      // global 16-key slice
            s16x8 mfr = *(const s16x8*)&mbase[k0 + ks * 16 + hi * 8];
            int vr0 = c, vr1 = 32 + c;
            s16x8 vf0 = *(const s16x8*)&Vb[vr0][((ks * 2 + hi) ^ (vr0 & 7)) * 8];
            s16x8 vf1 = *(const s16x8*)&Vb[vr1][((ks * 2 + hi) ^ (vr1 & 7)) * 8];
            __builtin_amdgcn_s_setprio(1);
#pragma unroll
            for (int qs = 0; qs < 2; qs++) {
                lacc[qs]  = MFMA32_BF16(pa[qs][ksl], mfr, lacc[qs]);
                o[qs][0]  = MFMA32_BF16(pa[qs][ksl], vf0, o[qs][0]);
                o[qs][1]  = MFMA32_BF16(pa[qs][ksl], vf1, o[qs][1]);
            }
            __builtin_amdgcn_s_setprio(0);
        }
    };

    issue(0, &Kl0[0][0], &Vl0[0][0]);
    __syncthreads();
    for (int it = 0; it < 32; it += 2) {
        int k0 = it * 64;
        if (it + 1 < 32) issue(k0 + 64, &Kl1[0][0], &Vl1[0][0]);
        compute(k0, Kl0, Vl0);
        __syncthreads();
        if (it + 2 < 32) issue(k0 + 128, &Kl0[0][0], &Vl0[0][0]);
        compute(k0 + 64, Kl1, Vl1);
        __syncthreads();
    }

    // ---- cross-wave reduction: khalf=1 partials -> khalf=0 ---------------
    // stride 49 floats/lane -> bank (lane*17 + r) % 32, conflict-free.
    float* red = (float*)ldsbuf;
#pragma unroll
    for (int qs = 0; qs < 2; qs++) {
        __syncthreads();
        if (khalf == 1) {
            float* dst = red + qhalf * 3136 + lane * 49;
#pragma unroll
            for (int r = 0; r < 16; r++) {
                dst[r] = o[qs][0][r]; dst[16 + r] = o[qs][1][r]; dst[32 + r] = lacc[qs][r];
            }
        }
        __syncthreads();
        if (khalf == 0) {
            const float* src = red + qhalf * 3136 + lane * 49;
#pragma unroll
            for (int r = 0; r < 16; r++) {
                o[qs][0][r] += src[r]; o[qs][1][r] += src[16 + r]; lacc[qs][r] += src[32 + r];
            }
        }
    }

    // epilogue (khalf==0 waves): row q = q0+qhalf*64+qs*32+(r&3)+8(r>>2)+4hi
    if (khalf == 0) {
#pragma unroll
        for (int qs = 0; qs < 2; qs++) {
            float linv[16];
#pragma unroll
            for (int r = 0; r < 16; r++) linv[r] = 1.0f / lacc[qs][r];
#pragma unroll
            for (int db = 0; db < 2; db++)
#pragma unroll
                for (int r = 0; r < 16; r++) {
                    int n = q0 + qhalf * 64 + qs * 32 + (r & 3) + 8 * (r >> 2) + 4 * hi;
                    Og[((size_t)b * N + n) * 1024 + h * 64 + db * 32 + c] =
                        f2bf(o[qs][db][r] * linv[r]);
                }
        }
    }
}

// ---------------------------------------------------------------------------
// Projection GEMM: out[4096,1024] = attno[4096,1024] @ w_proj^T + bias, fp32.
// 1D grid (512 = 8 x 64), XCD-chunked swizzle.
// ---------------------------------------------------------------------------
__global__ __launch_bounds__(256) void gemm_proj(const unsigned short* __restrict__ A,
                                                 const unsigned short* __restrict__ B,
                                                 float* __restrict__ C,
                                                 const float* __restrict__ bias) {
    const int NN = 1024, K = 1024;
    __shared__ unsigned short Al[128][64];
    __shared__ unsigned short Bl[64][64];
    const int tid  = threadIdx.x;
    const int lane = tid & 63;
    const int qd   = lane >> 4;
    const int cc   = lane & 15;
    const int wave = tid >> 6;
    const int wr   = wave >> 1, wc = wave & 1;
    int dd = blockIdx.x;                        // 512 = 8 x 64
    int sw = (dd & 7) * 64 + (dd >> 3);
    const int m0   = (sw >> 4) * 128, n0 = (sw & 15) * 64;
    unsigned short* Alf = &Al[0][0];
    unsigned short* Blf = &Bl[0][0];

    f32x4 acc[4][2];
#pragma unroll
    for (int i = 0; i < 4; i++)
#pragma unroll
        for (int j = 0; j < 2; j++) acc[i][j] = (f32x4){0.f, 0.f, 0.f, 0.f};

    for (int k0 = 0; k0 < K; k0 += 64) {
#pragma unroll
        for (int t = 0; t < 4; t++) {
            int idx = t * 256 + tid;
            int row = idx >> 3, sg = (idx & 7) ^ (row & 7);
            GLD_TO_LDS(A + (size_t)(m0 + row) * K + k0 + sg * 8, Alf + idx * 8);
        }
#pragma unroll
        for (int t = 0; t < 2; t++) {
            int idx = t * 256 + tid;
            int row = idx >> 3, sg = (idx & 7) ^ (row & 7);
            GLD_TO_LDS(B + (size_t)(n0 + row) * K + k0 + sg * 8, Blf + idx * 8);
        }
        __syncthreads();
#pragma unroll
        for (int ks = 0; ks < 64; ks += 32) {
            const int s4 = ks >> 3;
            s16x8 af[4], bf[2];
#pragma unroll
            for (int i = 0; i < 4; i++) {
                int r = wr * 64 + i * 16 + cc;
                af[i] = *(const s16x8*)&Al[r][((s4 + qd) ^ (r & 7)) * 8];
            }
#pragma unroll
            for (int j = 0; j < 2; j++) {
                int r = wc * 32 + j * 16 + cc;
                bf[j] = *(const s16x8*)&Bl[r][((s4 + qd) ^ (r & 7)) * 8];
            }
#pragma unroll
            for (int i = 0; i < 4; i++)
#pragma unroll
                for (int j = 0; j < 2; j++)
                    acc[i][j] = MFMA_BF16(af[i], bf[j], acc[i][j]);
        }
        __syncthreads();
    }
#pragma unroll
    for (int i = 0; i < 4; i++)
#pragma unroll
        for (int j = 0; j < 2; j++)
#pragma unroll
            for (int r = 0; r < 4; r++) {
                int row = m0 + wr * 64 + i * 16 + qd * 4 + r;
                int col = n0 + wc * 32 + j * 16 + cc;
                C[(size_t)row * NN + col] = acc[i][j][r] + bias[col];
            }
}

// ---------------------------------------------------------------------------
extern "C" void kernel_launch(void* const* d_in, const int* in_sizes, int n_in,
                              void* d_out, int out_size, void* d_ws, size_t ws_size,
                              hipStream_t stream) {
    const float* x      = (const float*)d_in[0];
    const float* w_qkv  = (const float*)d_in[1];
    const float* w_proj = (const float*)d_in[2];
    const float* b_proj = (const float*)d_in[3];
    const int*   mask   = (const int*)d_in[4];
    float* out = (float*)d_out;

    // workspace layout (bf16 elements), ~72 MB
    unsigned short* ws     = (unsigned short*)d_ws;
    unsigned short* xb     = ws;                                  // 4096*1024
    unsigned short* wqkvb  = xb     + (size_t)4096 * 1024;        // 3072*1024
    unsigned short* wprojb = wqkvb  + (size_t)3072 * 1024;        // 1024*1024
    unsigned short* qkv    = wprojb + (size_t)1024 * 1024;        // 4096*3072 (Q region used)
    unsigned short* Qm     = qkv    + (size_t)4096 * 3072;        // unused
    unsigned short* Km     = Qm     + (size_t)32 * 2048 * 64;
    unsigned short* Vtm    = Km     + (size_t)32 * 2048 * 64;
    unsigned short* attno  = Vtm    + (size_t)32 * 2048 * 64;     // 4096*1024
    unsigned short* maskbf = attno  + (size_t)4096 * 1024;        // 2*2048 bf16

    // converts (32B/thread) + perm16'd bf16 mask vector, one launch
    prep<<<4112, 256, 0, stream>>>(x, w_qkv, w_proj, mask, xb, wqkvb, wprojb, maskbf);
    // qkv = x @ w_qkv^T; K tiles rope->Km, V tiles mask+transpose+perm16->Vt
    gemm_bt<<<768, 256, 0, stream>>>(xb, wqkvb, mask, qkv, Km, Vtm, 4096, 3072, 1024);
    // attention: 128-row Q tiles, key-split waves, 32x32 MFMA, in-reg P,
    // in-reg Q-RoPE from qkv, LDS-staged K/V  (512 blocks = 8 x 64, XCD-swizzled)
    flash_attn<<<512, 256, 0, stream>>>(qkv, Km, Vtm, maskbf, attno);
    // out = attn_out @ w_proj^T + b_proj   (512 blocks = 8 x 64, XCD-swizzled)
    gemm_proj<<<512, 256, 0, stream>>>(attno, wprojb, out, b_proj);
}